// Round 5
// baseline (542.579 us; speedup 1.0000x reference)
//
#include <hip/hip_runtime.h>
#include <hip/hip_bf16.h>

#define B_ 64
#define N_ 2048
#define I_ 16
#define J_ 32
#define O_ 32
#define JO_ 1024

typedef __attribute__((ext_vector_type(8))) short bf16x8;
typedef __attribute__((ext_vector_type(16))) float f32x16;
typedef unsigned short u16;
typedef unsigned int u32;

__device__ __forceinline__ float bf2f(u16 u) {
  union { u32 i; float f; } c; c.i = ((u32)u) << 16; return c.f;
}
__device__ __forceinline__ u16 f2bf(float f) {
  union { float f; u32 i; } c; c.f = f;
  u32 r = (c.i + 0x7fffu + ((c.i >> 16) & 1u)) >> 16;
  return (u16)r;
}
__device__ __forceinline__ u32 pack2(float a, float b) {
  return (u32)f2bf(a) | ((u32)f2bf(b) << 16);
}
__device__ __forceinline__ u32 scale2(u32 p, float cv) {
  return pack2(bf2f((u16)(p & 0xffffu)) * cv, bf2f((u16)(p >> 16)) * cv);
}

// ---------------------------------------------------------------------------
// xconv: x f32 [b][n][i] -> xt bf16 [n][b][i]
// ---------------------------------------------------------------------------
__global__ __launch_bounds__(256) void xconv_kernel(
    const float* __restrict__ xf, u16* __restrict__ xt)
{
  const int idx = blockIdx.x * 256 + threadIdx.x;   // = b*2048 + n
  const int b = idx >> 11, n = idx & 2047;
  const float4* sp = (const float4*)(xf + (size_t)idx * 16);
  float4 f0 = sp[0], f1 = sp[1], f2 = sp[2], f3 = sp[3];
  uint4 d0, d1;
  d0.x = pack2(f0.x, f0.y); d0.y = pack2(f0.z, f0.w);
  d0.z = pack2(f1.x, f1.y); d0.w = pack2(f1.z, f1.w);
  d1.x = pack2(f2.x, f2.y); d1.y = pack2(f2.z, f2.w);
  d1.z = pack2(f3.x, f3.y); d1.w = pack2(f3.z, f3.w);
  uint4* dp = (uint4*)(xt + ((size_t)n * 64 + b) * 16);
  dp[0] = d0; dp[1] = d1;
}

// ---------------------------------------------------------------------------
// wconv: w f32 [n][jo][i] -> wb bf16 (same layout). 2M rows of 16.
// ---------------------------------------------------------------------------
__global__ __launch_bounds__(256) void wconv_kernel(
    const float* __restrict__ wf, u16* __restrict__ wb)
{
  const size_t row = (size_t)blockIdx.x * 256 + threadIdx.x;
  const float4* sp = (const float4*)(wf + row * 16);
  float4 f0 = sp[0], f1 = sp[1], f2 = sp[2], f3 = sp[3];
  uint4 d0, d1;
  d0.x = pack2(f0.x, f0.y); d0.y = pack2(f0.z, f0.w);
  d0.z = pack2(f1.x, f1.y); d0.w = pack2(f1.z, f1.w);
  d1.x = pack2(f2.x, f2.y); d1.y = pack2(f2.z, f2.w);
  d1.z = pack2(f3.x, f3.y); d1.w = pack2(f3.z, f3.w);
  uint4* dp = (uint4*)(wb + row * 16);
  dp[0] = d0; dp[1] = d1;
}

// ---------------------------------------------------------------------------
// SF kernel: s_sum[jo][b] += sum_n c[b,n,j] * pred[b,n,jo]
// MFMA 32x32x16: A = w[n] rows jo (M=32 = one j-tile), B = x cols b (N=32),
// K=16=I exact. c folded into x-frag per lane (col=b). acc stays in MFMA C
// across the whole n-chunk. grid (32 j, 2 half, 16 split), block 256.
// ---------------------------------------------------------------------------
#define SF_NPW 32

__global__ __launch_bounds__(256) void sf_kernel(
    const u16* __restrict__ xt, const u16* __restrict__ wb,
    const u16* __restrict__ ct, float* __restrict__ s_sum, int uniform)
{
  __shared__ float red[4][1024];
  const int tid = threadIdx.x;
  const int wave = tid >> 6, lane = tid & 63;
  const int l31 = lane & 31, h = lane >> 5;
  const int j = blockIdx.x, half = blockIdx.y, split = blockIdx.z;
  const int n0 = (split * 4 + wave) * SF_NPW;
  const int b = half * 32 + l31;
  f32x16 acc = {0.f, 0.f, 0.f, 0.f, 0.f, 0.f, 0.f, 0.f,
                0.f, 0.f, 0.f, 0.f, 0.f, 0.f, 0.f, 0.f};

  #pragma unroll 4
  for (int i = 0; i < SF_NPW; ++i) {
    const int n = n0 + i;
    // A-frag: w[n][j*32 + l31][i = h*8..+8]
    bf16x8 wfr = *(const bf16x8*)(wb + ((size_t)n * JO_ + j * 32 + l31) * 16 + h * 8);
    // B-frag: x[b][n][i = h*8..+8] from xt[n][b][i]
    bf16x8 xfr = *(const bf16x8*)(xt + ((size_t)n * 64 + b) * 16 + h * 8);
    if (!uniform) {
      const float cv = bf2f(ct[((size_t)j * N_ + n) * 64 + b]);
      union { bf16x8 v; u32 u[4]; } xx; xx.v = xfr;
      xx.u[0] = scale2(xx.u[0], cv); xx.u[1] = scale2(xx.u[1], cv);
      xx.u[2] = scale2(xx.u[2], cv); xx.u[3] = scale2(xx.u[3], cv);
      xfr = xx.v;
    }
    acc = __builtin_amdgcn_mfma_f32_32x32x16_bf16(wfr, xfr, acc, 0, 0, 0);
  }
  // C layout: col=lane&31 (=b32), row o = (r&3)+8*(r>>2)+4h
  #pragma unroll
  for (int r = 0; r < 16; ++r) {
    const int o = (r & 3) + 8 * (r >> 2) + 4 * h;
    red[wave][o * 32 + l31] = acc[r];
  }
  __syncthreads();
  #pragma unroll
  for (int k = 0; k < 4; ++k) {
    const int idx = tid + 256 * k;
    const int o = idx >> 5, b32 = idx & 31;
    const float sum = red[0][idx] + red[1][idx] + red[2][idx] + red[3][idx];
    atomicAdd(&s_sum[(size_t)(j * 32 + o) * 64 + half * 32 + b32], sum);
  }
}

// ---------------------------------------------------------------------------
// R kernel: squash over o from s_sum[jo][b].
// mode 0: write v f32 + vbf=f2bf(v); 1: write vbf=f2bf(v+vprev); 2: write out.
// grid 1024 (= 64 b x 16 jgroups), block 64 (2 j x 32 o).
// ---------------------------------------------------------------------------
__global__ __launch_bounds__(64) void r_kernel(
    const float* __restrict__ s_sum, float* __restrict__ v,
    const float* __restrict__ vprev, u16* __restrict__ vbf,
    float* __restrict__ out, int mode, float scale)
{
  const int tid = threadIdx.x;
  const int jj = tid >> 5, o = tid & 31;
  const int b = blockIdx.x >> 4, jg = blockIdx.x & 15;
  const int j = jg * 2 + jj;
  const float s = s_sum[(size_t)(j * 32 + o) * 64 + b] * scale;
  float sq = s * s;
  #pragma unroll
  for (int m = 16; m >= 1; m >>= 1) sq += __shfl_xor(sq, m, 64);
  const float sc = sq / (1.f + sq) * rsqrtf(sq + 1e-8f);
  const float vv = sc * s;
  const size_t off = (size_t)b * JO_ + j * 32 + o;
  if (mode == 0) { v[off] = vv; vbf[off] = f2bf(vv); }
  else if (mode == 1) { vbf[off] = f2bf(vv + vprev[off]); }
  else { out[off] = vv; }
}

// ---------------------------------------------------------------------------
// A kernel: per wave-n: pred tile (32 jo x 32 b) via MFMA 32x32x16 (w rows,
// x cols, K=16); dot rows with v (64KB swizzled LDS) -> ONE shfl_xor(32) per
// j; logits in 32 regs; in-lane softmax; c -> ct[j][n][b] bf16.
// grid (256 ngroups, 2 half), block 256 (4 waves x A_GN=2 n).
// ---------------------------------------------------------------------------
#define A_GN 2

__global__ __launch_bounds__(256, 2) void a_kernel(
    const u16* __restrict__ xt, const u16* __restrict__ wb,
    const u16* __restrict__ vbf, u16* __restrict__ ct)
{
  __shared__ u16 vq[32 * 1024];   // 64 KB, [b32][jo^((b32&15)<<2)]
  const int tid = threadIdx.x;
  const int wave = tid >> 6, lane = tid & 63;
  const int l31 = lane & 31, h = lane >> 5;
  const int group = blockIdx.x, half = blockIdx.y;

  // stage v (b-half, bf16) -> swizzled LDS, uint2 granularity
  {
    const u16* vsrc = vbf + (size_t)(half * 32) * JO_;
    for (int k = tid; k < 8192; k += 256) {
      const int b32 = k >> 8, jo = (k & 255) * 4;
      const uint2 val = *(const uint2*)(vsrc + b32 * JO_ + jo);
      *(uint2*)(vq + b32 * JO_ + (jo ^ ((b32 & 15) << 2))) = val;
    }
  }
  __syncthreads();

  const u16* vrow = vq + l31 * JO_;
  const int swz = (l31 & 15) << 2;
  const f32x16 zero16 = {0.f, 0.f, 0.f, 0.f, 0.f, 0.f, 0.f, 0.f,
                         0.f, 0.f, 0.f, 0.f, 0.f, 0.f, 0.f, 0.f};

  #pragma unroll 1
  for (int nl = 0; nl < A_GN; ++nl) {
    const int n = group * (4 * A_GN) + wave * A_GN + nl;
    // B-frag: x[b = half*32+l31][i = h*8..+8]
    const bf16x8 xfr =
        *(const bf16x8*)(xt + ((size_t)n * 64 + half * 32 + l31) * 16 + h * 8);
    float lg[J_];
    #pragma unroll
    for (int t = 0; t < 32; ++t) {
      // A-frag: w[n][t*32 + l31][i = h*8..+8]
      const bf16x8 wfr =
          *(const bf16x8*)(wb + ((size_t)n * JO_ + t * 32 + l31) * 16 + h * 8);
      f32x16 p = __builtin_amdgcn_mfma_f32_32x32x16_bf16(wfr, xfr, zero16, 0, 0, 0);
      // dot rows with v: reg r -> o = (r&3) + 8*(r>>2) + 4h
      float sg0 = 0.f, sg1 = 0.f, sg2 = 0.f, sg3 = 0.f;
      #pragma unroll
      for (int g = 0; g < 4; ++g) {
        const int base = t * 32 + g * 8 + h * 4;
        const ushort4 v4 = *(const ushort4*)(vrow + (base ^ swz));
        float pg = p[g * 4 + 0] * bf2f(v4.x) + p[g * 4 + 1] * bf2f(v4.y)
                 + p[g * 4 + 2] * bf2f(v4.z) + p[g * 4 + 3] * bf2f(v4.w);
        if (g == 0) sg0 = pg; else if (g == 1) sg1 = pg;
        else if (g == 2) sg2 = pg; else sg3 = pg;
      }
      float s = (sg0 + sg1) + (sg2 + sg3);
      s += __shfl_xor(s, 32, 64);     // combine h-halves (same col b)
      lg[t] = s;
    }
    // in-lane softmax over 32 j
    float mx = lg[0];
    #pragma unroll
    for (int t = 1; t < 32; ++t) mx = fmaxf(mx, lg[t]);
    float sum = 0.f;
    #pragma unroll
    for (int t = 0; t < 32; ++t) { lg[t] = __expf(lg[t] - mx); sum += lg[t]; }
    const float inv = 1.f / sum;
    // store c: h=0 lanes write j=0..15, h=1 lanes write j=16..31
    #pragma unroll
    for (int jj = 0; jj < 16; ++jj) {
      const float c0 = lg[jj] * inv, c1 = lg[16 + jj] * inv;
      const float cc = h ? c1 : c0;
      const int j = h * 16 + jj;
      ct[((size_t)j * N_ + n) * 64 + half * 32 + l31] = f2bf(cc);
    }
  }
}

// ---------------------------------------------------------------------------
extern "C" void kernel_launch(void* const* d_in, const int* in_sizes, int n_in,
                              void* d_out, int out_size, void* d_ws, size_t ws_size,
                              hipStream_t stream) {
  const float* x = (const float*)d_in[0];
  const float* w = (const float*)d_in[1];
  float* out = (float*)d_out;
  char* ws = (char*)d_ws;
  // layout: wb 64MB | ct 8MB | xt 4MB | s_sum 256K | v0 256K | vbf 128K
  u16*   wb    = (u16*)ws;
  u16*   ct    = (u16*)(ws + (size_t)64 * 1024 * 1024);
  u16*   xt    = (u16*)(ws + (size_t)72 * 1024 * 1024);
  float* s_sum = (float*)(ws + (size_t)76 * 1024 * 1024);
  float* v0    = (float*)(ws + (size_t)76 * 1024 * 1024 + 262144);
  u16*   vbf   = (u16*)(ws + (size_t)76 * 1024 * 1024 + 2 * 262144);

  const size_t s_bytes = (size_t)JO_ * B_ * sizeof(float);
  dim3 sfg(32, 2, 16), sfb(256);
  dim3 ag(256, 2), ab(256);
  dim3 rg(1024), rb(64);

  xconv_kernel<<<dim3(512), dim3(256), 0, stream>>>(x, xt);
  wconv_kernel<<<dim3(8192), dim3(256), 0, stream>>>(w, wb);
  // iter 0: uniform c folded as scale=1/32 in r_kernel
  hipMemsetAsync(s_sum, 0, s_bytes, stream);
  sf_kernel<<<sfg, sfb, 0, stream>>>(xt, wb, ct, s_sum, 1);
  r_kernel<<<rg, rb, 0, stream>>>(s_sum, v0, v0, vbf, out, 0, 0.03125f);
  // iter 1
  a_kernel<<<ag, ab, 0, stream>>>(xt, wb, vbf, ct);
  hipMemsetAsync(s_sum, 0, s_bytes, stream);
  sf_kernel<<<sfg, sfb, 0, stream>>>(xt, wb, ct, s_sum, 0);
  r_kernel<<<rg, rb, 0, stream>>>(s_sum, v0, v0, vbf, out, 1, 1.0f);
  // iter 2 (logits = pred . (v0+v1) via vbf)
  a_kernel<<<ag, ab, 0, stream>>>(xt, wb, vbf, ct);
  hipMemsetAsync(s_sum, 0, s_bytes, stream);
  sf_kernel<<<sfg, sfb, 0, stream>>>(xt, wb, ct, s_sum, 0);
  r_kernel<<<rg, rb, 0, stream>>>(s_sum, v0, v0, vbf, out, 2, 1.0f);
}

// Round 6
// 450.402 us; speedup vs baseline: 1.2047x; 1.2047x over previous
//
#include <hip/hip_runtime.h>
#include <hip/hip_bf16.h>

#define B_ 64
#define N_ 2048
#define I_ 16
#define J_ 32
#define O_ 32
#define JO_ 1024

typedef __attribute__((ext_vector_type(8))) short bf16x8;
typedef __attribute__((ext_vector_type(16))) float f32x16;
typedef unsigned short u16;
typedef unsigned int u32;

__device__ __forceinline__ float bf2f(u16 u) {
  union { u32 i; float f; } c; c.i = ((u32)u) << 16; return c.f;
}
__device__ __forceinline__ u16 f2bf(float f) {
  union { float f; u32 i; } c; c.f = f;
  u32 r = (c.i + 0x7fffu + ((c.i >> 16) & 1u)) >> 16;
  return (u16)r;
}
__device__ __forceinline__ u32 pack2(float a, float b) {
  return (u32)f2bf(a) | ((u32)f2bf(b) << 16);
}
__device__ __forceinline__ u32 scale2(u32 p, float cv) {
  return pack2(bf2f((u16)(p & 0xffffu)) * cv, bf2f((u16)(p >> 16)) * cv);
}

// ---------------------------------------------------------------------------
// xconv: x f32 [b][n][i] -> xt bf16 [n][b][i]
// ---------------------------------------------------------------------------
__global__ __launch_bounds__(256) void xconv_kernel(
    const float* __restrict__ xf, u16* __restrict__ xt)
{
  const int idx = blockIdx.x * 256 + threadIdx.x;   // = b*2048 + n
  const int b = idx >> 11, n = idx & 2047;
  const float4* sp = (const float4*)(xf + (size_t)idx * 16);
  float4 f0 = sp[0], f1 = sp[1], f2 = sp[2], f3 = sp[3];
  uint4 d0, d1;
  d0.x = pack2(f0.x, f0.y); d0.y = pack2(f0.z, f0.w);
  d0.z = pack2(f1.x, f1.y); d0.w = pack2(f1.z, f1.w);
  d1.x = pack2(f2.x, f2.y); d1.y = pack2(f2.z, f2.w);
  d1.z = pack2(f3.x, f3.y); d1.w = pack2(f3.z, f3.w);
  uint4* dp = (uint4*)(xt + ((size_t)n * 64 + b) * 16);
  dp[0] = d0; dp[1] = d1;
}

// ---------------------------------------------------------------------------
// wconv: w f32 [n][jo][i] -> wb bf16 (same layout). 2M rows of 16.
// ---------------------------------------------------------------------------
__global__ __launch_bounds__(256) void wconv_kernel(
    const float* __restrict__ wf, u16* __restrict__ wb)
{
  const size_t row = (size_t)blockIdx.x * 256 + threadIdx.x;
  const float4* sp = (const float4*)(wf + row * 16);
  float4 f0 = sp[0], f1 = sp[1], f2 = sp[2], f3 = sp[3];
  uint4 d0, d1;
  d0.x = pack2(f0.x, f0.y); d0.y = pack2(f0.z, f0.w);
  d0.z = pack2(f1.x, f1.y); d0.w = pack2(f1.z, f1.w);
  d1.x = pack2(f2.x, f2.y); d1.y = pack2(f2.z, f2.w);
  d1.z = pack2(f3.x, f3.y); d1.w = pack2(f3.z, f3.w);
  uint4* dp = (uint4*)(wb + row * 16);
  dp[0] = d0; dp[1] = d1;
}

// ---------------------------------------------------------------------------
// SF kernel: s_sum[jo][b] += sum_n c[b,n,j] * pred[b,n,jo]
// MFMA 32x32x16: A = w[n] rows (M=32 = one j-tile), B = x cols b, K=16=I.
// Dual-half: both b-halves per wave, sharing the A fragment (wb read once).
// grid (32 j, 16 split), block 256.
// ---------------------------------------------------------------------------
#define SF_NPW 32

__global__ __launch_bounds__(256) void sf_kernel(
    const u16* __restrict__ xt, const u16* __restrict__ wb,
    const u16* __restrict__ ct, float* __restrict__ s_sum, int uniform)
{
  __shared__ float red[4][2048];   // 32 KB
  const int tid = threadIdx.x;
  const int wave = tid >> 6, lane = tid & 63;
  const int l31 = lane & 31, h = lane >> 5;
  const int j = blockIdx.x, split = blockIdx.y;
  const int n0 = (split * 4 + wave) * SF_NPW;
  f32x16 acc0 = {0.f, 0.f, 0.f, 0.f, 0.f, 0.f, 0.f, 0.f,
                 0.f, 0.f, 0.f, 0.f, 0.f, 0.f, 0.f, 0.f};
  f32x16 acc1 = acc0;

  #pragma unroll 4
  for (int i = 0; i < SF_NPW; ++i) {
    const int n = n0 + i;
    // A-frag: w[n][j*32 + l31][i = h*8..+8]
    bf16x8 wfr = *(const bf16x8*)(wb + ((size_t)n * JO_ + j * 32 + l31) * 16 + h * 8);
    // B-frags: x cols b = l31 and 32+l31
    bf16x8 x0 = *(const bf16x8*)(xt + ((size_t)n * 64 + l31) * 16 + h * 8);
    bf16x8 x1 = *(const bf16x8*)(xt + ((size_t)n * 64 + 32 + l31) * 16 + h * 8);
    if (!uniform) {
      const float cv0 = bf2f(ct[((size_t)j * N_ + n) * 64 + l31]);
      const float cv1 = bf2f(ct[((size_t)j * N_ + n) * 64 + 32 + l31]);
      union { bf16x8 v; u32 u[4]; } a, b2;
      a.v = x0; b2.v = x1;
      a.u[0] = scale2(a.u[0], cv0); a.u[1] = scale2(a.u[1], cv0);
      a.u[2] = scale2(a.u[2], cv0); a.u[3] = scale2(a.u[3], cv0);
      b2.u[0] = scale2(b2.u[0], cv1); b2.u[1] = scale2(b2.u[1], cv1);
      b2.u[2] = scale2(b2.u[2], cv1); b2.u[3] = scale2(b2.u[3], cv1);
      x0 = a.v; x1 = b2.v;
    }
    acc0 = __builtin_amdgcn_mfma_f32_32x32x16_bf16(wfr, x0, acc0, 0, 0, 0);
    acc1 = __builtin_amdgcn_mfma_f32_32x32x16_bf16(wfr, x1, acc1, 0, 0, 0);
  }
  // C layout: col=lane&31 (=b), row o = (r&3)+8*(r>>2)+4h
  #pragma unroll
  for (int r = 0; r < 16; ++r) {
    const int o = (r & 3) + 8 * (r >> 2) + 4 * h;
    red[wave][o * 64 + l31] = acc0[r];
    red[wave][o * 64 + 32 + l31] = acc1[r];
  }
  __syncthreads();
  #pragma unroll
  for (int k = 0; k < 8; ++k) {
    const int idx = tid + 256 * k;
    const int o = idx >> 6, b = idx & 63;
    const float sum = red[0][idx] + red[1][idx] + red[2][idx] + red[3][idx];
    atomicAdd(&s_sum[(size_t)(j * 32 + o) * 64 + b], sum);
  }
}

// ---------------------------------------------------------------------------
// R kernel: squash over o from s_sum[jo][b].
// mode 0: write v f32 + vbf=f2bf(v); 1: vbf=f2bf(v+vprev); 2: write out.
// grid 1024 (= 64 b x 16 jgroups), block 64 (2 j x 32 o).
// ---------------------------------------------------------------------------
__global__ __launch_bounds__(64) void r_kernel(
    const float* __restrict__ s_sum, float* __restrict__ v,
    const float* __restrict__ vprev, u16* __restrict__ vbf,
    float* __restrict__ out, int mode, float scale)
{
  const int tid = threadIdx.x;
  const int jj = tid >> 5, o = tid & 31;
  const int b = blockIdx.x >> 4, jg = blockIdx.x & 15;
  const int j = jg * 2 + jj;
  const float s = s_sum[(size_t)(j * 32 + o) * 64 + b] * scale;
  float sq = s * s;
  #pragma unroll
  for (int m = 16; m >= 1; m >>= 1) sq += __shfl_xor(sq, m, 64);
  const float sc = sq / (1.f + sq) * rsqrtf(sq + 1e-8f);
  const float vv = sc * s;
  const size_t off = (size_t)b * JO_ + j * 32 + o;
  if (mode == 0) { v[off] = vv; vbf[off] = f2bf(vv); }
  else if (mode == 1) { vbf[off] = f2bf(vv + vprev[off]); }
  else { out[off] = vv; }
}

// ---------------------------------------------------------------------------
// A kernel: one n per wave, BOTH b-halves (wb read once). Per t (j-tile):
// 1 wfr + 2 MFMA; dot rows with vbf straight from global (the 4 ushort4
// loads per (t,half) hit one 64B line -> L1/L2). One shfl per half.
// In-lane softmax over 32 j-logits; ct[j][n][b] bf16. No LDS, no barriers.
// grid 512, block 256 (4 waves = 4 n). #pragma unroll 2 bounds liveness.
// ---------------------------------------------------------------------------
__global__ __launch_bounds__(256, 2) void a_kernel(
    const u16* __restrict__ xt, const u16* __restrict__ wb,
    const u16* __restrict__ vbf, u16* __restrict__ ct)
{
  const int tid = threadIdx.x;
  const int wave = tid >> 6, lane = tid & 63;
  const int l31 = lane & 31, h = lane >> 5;
  const int n = blockIdx.x * 4 + wave;
  const f32x16 zero16 = {0.f, 0.f, 0.f, 0.f, 0.f, 0.f, 0.f, 0.f,
                         0.f, 0.f, 0.f, 0.f, 0.f, 0.f, 0.f, 0.f};

  // B-frags: x cols b = l31 and 32+l31
  const bf16x8 x0 = *(const bf16x8*)(xt + ((size_t)n * 64 + l31) * 16 + h * 8);
  const bf16x8 x1 = *(const bf16x8*)(xt + ((size_t)n * 64 + 32 + l31) * 16 + h * 8);
  const u16* vrow0 = vbf + (size_t)l31 * JO_;
  const u16* vrow1 = vbf + (size_t)(32 + l31) * JO_;

  float lg0[J_], lg1[J_];
  #pragma unroll 2
  for (int t = 0; t < 32; ++t) {
    const bf16x8 wfr =
        *(const bf16x8*)(wb + ((size_t)n * JO_ + t * 32 + l31) * 16 + h * 8);
    f32x16 p0 = __builtin_amdgcn_mfma_f32_32x32x16_bf16(wfr, x0, zero16, 0, 0, 0);
    f32x16 p1 = __builtin_amdgcn_mfma_f32_32x32x16_bf16(wfr, x1, zero16, 0, 0, 0);
    float s0 = 0.f, s1 = 0.f;
    #pragma unroll
    for (int g = 0; g < 4; ++g) {
      const int base = t * 32 + g * 8 + h * 4;   // o = g*8 + h*4 + 0..3
      const ushort4 va = *(const ushort4*)(vrow0 + base);
      const ushort4 vb = *(const ushort4*)(vrow1 + base);
      s0 += p0[g * 4 + 0] * bf2f(va.x) + p0[g * 4 + 1] * bf2f(va.y)
          + p0[g * 4 + 2] * bf2f(va.z) + p0[g * 4 + 3] * bf2f(va.w);
      s1 += p1[g * 4 + 0] * bf2f(vb.x) + p1[g * 4 + 1] * bf2f(vb.y)
          + p1[g * 4 + 2] * bf2f(vb.z) + p1[g * 4 + 3] * bf2f(vb.w);
    }
    s0 += __shfl_xor(s0, 32, 64);   // combine h-halves (same col b)
    s1 += __shfl_xor(s1, 32, 64);
    lg0[t] = s0; lg1[t] = s1;
  }
  // in-lane softmax over 32 j for b=l31 (lg0) and b=32+l31 (lg1)
  float mx0 = lg0[0], mx1 = lg1[0];
  #pragma unroll
  for (int t = 1; t < 32; ++t) { mx0 = fmaxf(mx0, lg0[t]); mx1 = fmaxf(mx1, lg1[t]); }
  float sm0 = 0.f, sm1 = 0.f;
  #pragma unroll
  for (int t = 0; t < 32; ++t) {
    lg0[t] = __expf(lg0[t] - mx0); sm0 += lg0[t];
    lg1[t] = __expf(lg1[t] - mx1); sm1 += lg1[t];
  }
  const float i0 = 1.f / sm0, i1 = 1.f / sm1;
  // store c: h=0 lanes write j=0..15, h=1 lanes write j=16..31
  #pragma unroll
  for (int jj = 0; jj < 16; ++jj) {
    const int j = h * 16 + jj;
    const float c0 = (h ? lg0[16 + jj] : lg0[jj]) * i0;
    const float c1 = (h ? lg1[16 + jj] : lg1[jj]) * i1;
    const size_t base = ((size_t)j * N_ + n) * 64;
    ct[base + l31] = f2bf(c0);
    ct[base + 32 + l31] = f2bf(c1);
  }
}

// ---------------------------------------------------------------------------
extern "C" void kernel_launch(void* const* d_in, const int* in_sizes, int n_in,
                              void* d_out, int out_size, void* d_ws, size_t ws_size,
                              hipStream_t stream) {
  const float* x = (const float*)d_in[0];
  const float* w = (const float*)d_in[1];
  float* out = (float*)d_out;
  char* ws = (char*)d_ws;
  // layout: wb 64MB | ct 8MB | xt 4MB | s_sum 256K | v0 256K | vbf 128K
  u16*   wb    = (u16*)ws;
  u16*   ct    = (u16*)(ws + (size_t)64 * 1024 * 1024);
  u16*   xt    = (u16*)(ws + (size_t)72 * 1024 * 1024);
  float* s_sum = (float*)(ws + (size_t)76 * 1024 * 1024);
  float* v0    = (float*)(ws + (size_t)76 * 1024 * 1024 + 262144);
  u16*   vbf   = (u16*)(ws + (size_t)76 * 1024 * 1024 + 2 * 262144);

  const size_t s_bytes = (size_t)JO_ * B_ * sizeof(float);
  dim3 sfg(32, 16), sfb(256);
  dim3 ag(512), ab(256);
  dim3 rg(1024), rb(64);

  xconv_kernel<<<dim3(512), dim3(256), 0, stream>>>(x, xt);
  wconv_kernel<<<dim3(8192), dim3(256), 0, stream>>>(w, wb);
  // iter 0: uniform c folded as scale=1/32 in r_kernel
  hipMemsetAsync(s_sum, 0, s_bytes, stream);
  sf_kernel<<<sfg, sfb, 0, stream>>>(xt, wb, ct, s_sum, 1);
  r_kernel<<<rg, rb, 0, stream>>>(s_sum, v0, v0, vbf, out, 0, 0.03125f);
  // iter 1
  a_kernel<<<ag, ab, 0, stream>>>(xt, wb, vbf, ct);
  hipMemsetAsync(s_sum, 0, s_bytes, stream);
  sf_kernel<<<sfg, sfb, 0, stream>>>(xt, wb, ct, s_sum, 0);
  r_kernel<<<rg, rb, 0, stream>>>(s_sum, v0, v0, vbf, out, 1, 1.0f);
  // iter 2 (logits = pred . (v0+v1) via vbf)
  a_kernel<<<ag, ab, 0, stream>>>(xt, wb, vbf, ct);
  hipMemsetAsync(s_sum, 0, s_bytes, stream);
  sf_kernel<<<sfg, sfb, 0, stream>>>(xt, wb, ct, s_sum, 0);
  r_kernel<<<rg, rb, 0, stream>>>(s_sum, v0, v0, vbf, out, 2, 1.0f);
}